// Round 9
// baseline (44.874 us; speedup 1.0000x reference)
//
#include <hip/hip_runtime.h>
#include <math.h>

#define H    1024
#define NH   16
#define HD   128
#define ID   2048
#define EPS  1e-6f
#define NBLK 256
#define NTHR 1024

// ws float layout:
// [0..16)    cnt1[16]  (int)   matvec-done counters per head (target 17)
// [16..32)   cnt2[16]  (int)   ypart-done counters per head (target 16)
// [32]       cntZ      (int)   out-zero rendezvous (target 256)
// [33..64)   pad
// [64..2112) ypart[16][128]    (atomicAdd accumulated)
// ---- memset zeroes bytes [0, 8448) each call ----
// [2112..8256)  qkv q|k|v (6144)   (atomicExch written / atomic read)
// [8256..10304) zsig (2048)
// [10304..10320) decay (16)

#define ALOAD(p)      __hip_atomic_load((p), __ATOMIC_RELAXED, __HIP_MEMORY_SCOPE_AGENT)
#define ALOAD_ACQ(p)  __hip_atomic_load((p), __ATOMIC_ACQUIRE, __HIP_MEMORY_SCOPE_AGENT)
#define AADD_REL(p,v) __hip_atomic_fetch_add((p), (v), __ATOMIC_RELEASE, __HIP_MEMORY_SCOPE_AGENT)

__global__ __launch_bounds__(NTHR) void fused_qwen_linattn(
    const float* __restrict__ x,
    const float* __restrict__ state_in,
    const float* __restrict__ conv,
    const float* __restrict__ Wqkv,
    const float* __restrict__ Wz,
    const float* __restrict__ Wa,
    const float* __restrict__ normw,
    const float* __restrict__ Wout,
    float* __restrict__ out,
    float* __restrict__ state_out,
    float* __restrict__ conv_out,
    float* __restrict__ ws)
{
    int*   cnt1  = (int*)ws;
    int*   cnt2  = cnt1 + 16;
    int*   cntZ  = cnt1 + 32;
    float* ypart = ws + 64;
    float* wqkvb = ws + 2112;
    float* wzsig = ws + 8256;
    float* wdec  = ws + 10304;

    const int b    = blockIdx.x;
    const int t    = threadIdx.x;
    const int wave = t >> 6;
    const int lane = t & 63;
    const int s    = b >> 4;    // d-slice / out-row-slice
    const int h    = b & 15;    // head (blocks of head h share b%16 -> same XCD)

    __shared__ float lds_q[HD], lds_k[HD], lds_v[HD], lds_z[HD];
    __shared__ float lds_part[8][HD];
    __shared__ float lds_g[HD];
    __shared__ float red2[2];
    __shared__ float lds_decay;

    // ---- early independent register preloads (overlap the matvec) ----
    const int sd = t >> 7, se = t & 127;
    const size_t sidx = (size_t)h * HD * HD + (size_t)(s * 8 + sd) * HD + se;
    const float sv = state_in[sidx];

    const int rl = t >> 4, j = t & 15;
    const int orow = s * 64 + rl;
    const float4* wrow = (const float4*)(Wout + (size_t)orow * ID + h * HD);
    const float4 w0 = wrow[2 * j];
    const float4 w1 = wrow[2 * j + 1];

    const float nw = (t < HD) ? normw[t] : 0.f;

    // conv passthrough: 18 float4 per block
    if (t < 18) ((float4*)conv_out)[b * 18 + t] = ((const float4*)conv)[b * 18 + t];
    // out zero via atomics (coherent vs later atomicAdd)
    if (t < 4) atomicExch(&out[4 * b + t], 0.f);

    // ================= Phase 0: matvec (2 rows per wave) =================
    {
        const float4* x4 = (const float4*)x;
        float4 xv[4];
#pragma unroll
        for (int i = 0; i < 4; ++i) xv[i] = x4[lane + 64 * i];

        const int r0 = b * 32 + wave * 2;     // 0..8190, both rows same region
        const float* basep = (r0 < 3 * ID) ? (Wqkv + (size_t)r0 * H)
                                           : (Wz + (size_t)(r0 - 3 * ID) * H);
        const float4* b4 = (const float4*)basep;
        float4 wa[4], wb[4];
#pragma unroll
        for (int i = 0; i < 4; ++i) { wa[i] = b4[lane + 64 * i]; wb[i] = b4[256 + lane + 64 * i]; }
        float a0 = 0.f, a1 = 0.f;
#pragma unroll
        for (int i = 0; i < 4; ++i) {
            a0 += wa[i].x * xv[i].x + wa[i].y * xv[i].y + wa[i].z * xv[i].z + wa[i].w * xv[i].w;
            a1 += wb[i].x * xv[i].x + wb[i].y * xv[i].y + wb[i].z * xv[i].z + wb[i].w * xv[i].w;
        }
#pragma unroll
        for (int off = 32; off > 0; off >>= 1) {
            a0 += __shfl_down(a0, off, 64);
            a1 += __shfl_down(a1, off, 64);
        }
        if (lane == 0) {
            if (r0 < 3 * ID) {
                atomicExch(&wqkvb[r0], a0);
                atomicExch(&wqkvb[r0 + 1], a1);
            } else {
                atomicExch(&wzsig[r0 - 3 * ID],     a0 / (1.f + expf(-a0)));
                atomicExch(&wzsig[r0 - 3 * ID + 1], a1 / (1.f + expf(-a1)));
            }
        }
        // 16 W_a rows: block b<16, wave 15 takes a 3rd row
        if (b < NH && wave == 15) {
            const float4* a4 = (const float4*)(Wa + (size_t)b * H);
            float aa = 0.f;
#pragma unroll
            for (int i = 0; i < 4; ++i) {
                float4 wv = a4[lane + 64 * i];
                aa += wv.x * xv[i].x + wv.y * xv[i].y + wv.z * xv[i].z + wv.w * xv[i].w;
            }
#pragma unroll
            for (int off = 32; off > 0; off >>= 1) aa += __shfl_down(aa, off, 64);
            if (lane == 0) atomicExch(&wdec[b], 1.f / (1.f + expf(-aa)));
        }
    }
    __syncthreads();
    if (t == 0) {
        AADD_REL(cntZ, 1);
        AADD_REL(&cnt1[(b & 63) >> 2], 1);   // q/k/v/z contribution
        if (b < NH) AADD_REL(&cnt1[b], 1);   // a-row contribution
    }

    // ================= wait for this head's inputs =================
    if (t == 0) { while (ALOAD_ACQ(&cnt1[h]) < 17) {} }
    __syncthreads();

    // stage head params into LDS via coherent atomic loads
    if (t < 128)       lds_q[t]       = ALOAD(&wqkvb[h * HD + t]);
    else if (t < 256)  lds_k[t - 128] = ALOAD(&wqkvb[ID + h * HD + (t - 128)]);
    else if (t < 384)  lds_v[t - 256] = ALOAD(&wqkvb[2 * ID + h * HD + (t - 256)]);
    else if (t < 512)  lds_z[t - 384] = ALOAD(&wzsig[h * HD + (t - 384)]);
    else if (t == 512) lds_decay      = ALOAD(&wdec[h]);
    __syncthreads();

    // ================= Phase 1: state update + ypart =================
    {
        const int d = s * 8 + sd;
        const float sn = sv * lds_decay + lds_k[d] * lds_v[se];
        state_out[sidx] = sn;
        lds_part[sd][se] = lds_q[d] * sn;
    }
    __syncthreads();
    if (t < HD) {
        float y8 = 0.f;
#pragma unroll
        for (int d2 = 0; d2 < 8; ++d2) y8 += lds_part[d2][t];
        atomicAdd(&ypart[h * HD + t], y8);
    }
    __syncthreads();
    if (t == 0) {
        AADD_REL(&cnt2[h], 1);
        while (ALOAD_ACQ(&cnt2[h]) < 16) {}
    }
    __syncthreads();

    // ================= Phase 2: RMSNorm + gate =================
    float yv = 0.f;
    if (t < HD) {
        yv = ALOAD(&ypart[h * HD + t]);
        float s2 = yv * yv;
#pragma unroll
        for (int off = 1; off < 64; off <<= 1) s2 += __shfl_xor(s2, off, 64);
        if (lane == 0) red2[t >> 6] = s2;
    }
    __syncthreads();
    if (t < HD) {
        const float scale = rsqrtf((red2[0] + red2[1]) * (1.f / HD) + EPS);
        lds_g[t] = yv * scale * nw * lds_z[t];
    }
    if (t == 0) { while (ALOAD_ACQ(cntZ) < NBLK) {} }   // out-zeros done (long ago)
    __syncthreads();

    // ================= Phase 3: Wout partial from registers =================
    {
        const float4* g4 = (const float4*)lds_g;
        const float4 g0 = g4[2 * j], g1 = g4[2 * j + 1];
        float a = w0.x * g0.x + w0.y * g0.y + w0.z * g0.z + w0.w * g0.w
                + w1.x * g1.x + w1.y * g1.y + w1.z * g1.z + w1.w * g1.w;
        a += __shfl_xor(a, 1, 64);
        a += __shfl_xor(a, 2, 64);
        a += __shfl_xor(a, 4, 64);
        a += __shfl_xor(a, 8, 64);
        if (j == 0) atomicAdd(&out[orow], a);
    }
}

extern "C" void kernel_launch(void* const* d_in, const int* in_sizes, int n_in,
                              void* d_out, int out_size, void* d_ws, size_t ws_size,
                              hipStream_t stream) {
    const float* x     = (const float*)d_in[0];
    const float* state = (const float*)d_in[1];
    const float* conv  = (const float*)d_in[2];
    const float* Wqkv  = (const float*)d_in[3];
    const float* Wz    = (const float*)d_in[4];
    const float* Wa    = (const float*)d_in[5];
    const float* normw = (const float*)d_in[6];
    const float* Wout  = (const float*)d_in[7];

    float* out       = (float*)d_out;                    // [1024]
    float* new_state = out + H;                          // [16*128*128]
    float* conv_out  = new_state + (size_t)NH * HD * HD; // [18432]
    float* ws        = (float*)d_ws;

    // zero sync counters + ypart accumulator (replay-safe)
    hipMemsetAsync(ws, 0, 2112 * sizeof(float), stream);

    fused_qwen_linattn<<<NBLK, NTHR, 0, stream>>>(
        x, state, conv, Wqkv, Wz, Wa, normw, Wout,
        out, new_state, conv_out, ws);
}

// Round 10
// 26.308 us; speedup vs baseline: 1.7057x; 1.7057x over previous
//
#include <hip/hip_runtime.h>
#include <math.h>

#define H    1024
#define NH   16
#define HD   128
#define ID   2048
#define EPS  1e-6f

// K1: qkv (6144) + a (16) rows, 1 row/wave, 4 waves/block
#define K1_ROWS (3 * ID + NH)            // 6160
#define K1_MATVEC_BLOCKS (K1_ROWS / 4)   // 1540
#define CONV_BLOCKS 18                   // 4608 float4

typedef float v4f __attribute__((ext_vector_type(4)));

// ws float layout:
// [0..16)      cnt[16] (int)   per-head rendezvous counters (target 16)
// [16..64)     pad
// [64..2112)   ypart[16][128]  (atomicAdd accumulated; zeroed by K1)
// [2112..4160) zsig[2048]      (atomicExch written by K2)
// [4160..10304) qkv q|k|v      (plain stores by K1)
// [10304..10320) decay[16]     (plain stores by K1)

#define ALOAD(p)      __hip_atomic_load((p), __ATOMIC_RELAXED, __HIP_MEMORY_SCOPE_AGENT)
#define ALOAD_ACQ(p)  __hip_atomic_load((p), __ATOMIC_ACQUIRE, __HIP_MEMORY_SCOPE_AGENT)
#define AADD_REL(p,v) __hip_atomic_fetch_add((p), (v), __ATOMIC_RELEASE, __HIP_MEMORY_SCOPE_AGENT)
#define AXCH(p,v)     __hip_atomic_exchange((p), (v), __ATOMIC_RELAXED, __HIP_MEMORY_SCOPE_AGENT)

__device__ __forceinline__ float waveReduceSum(float v) {
#pragma unroll
    for (int off = 32; off > 0; off >>= 1) v += __shfl_down(v, off, 64);
    return v;
}

// Kernel 1: qkv + a matvec (1 row/wave), conv passthrough, out/ws zeroing.
__global__ __launch_bounds__(256) void matvec_qkva(
    const float* __restrict__ x,
    const float* __restrict__ Wqkv,
    const float* __restrict__ Wa,
    const float* __restrict__ conv,
    float* __restrict__ conv_out,
    float* __restrict__ out,
    float* __restrict__ ws)
{
    if (blockIdx.x >= K1_MATVEC_BLOCKS) {
        const int cb = blockIdx.x - K1_MATVEC_BLOCKS;
        const int i = cb * 256 + threadIdx.x;
        ((float4*)conv_out)[i] = ((const float4*)conv)[i];
        if (cb == 0) {   // zero out[1024]
            float4 z4 = {0.f, 0.f, 0.f, 0.f};
            ((float4*)out)[threadIdx.x] = z4;
        } else if (cb == 1) {   // zero cnt+ypart region [0, 2112)
            for (int k = threadIdx.x; k < 2112; k += 256) ws[k] = 0.f;
        }
        return;
    }

    float* ws_qkv   = ws + 4160;
    float* ws_decay = ws + 10304;

    const int wave = threadIdx.x >> 6;
    const int lane = threadIdx.x & 63;
    const int r = blockIdx.x * 4 + wave;   // 0..6159

    const float* row = (r < 3 * ID) ? (Wqkv + (size_t)r * H)
                                    : (Wa + (size_t)(r - 3 * ID) * H);
    const float4* row4 = (const float4*)row;
    const float4* x4   = (const float4*)x;

    float acc = 0.f;
#pragma unroll
    for (int i = 0; i < 4; ++i) {
        float4 w  = row4[lane + 64 * i];
        float4 xv = x4[lane + 64 * i];
        acc += w.x * xv.x + w.y * xv.y + w.z * xv.z + w.w * xv.w;
    }
    acc = waveReduceSum(acc);
    if (lane == 0) {
        if (r < 3 * ID) ws_qkv[r] = acc;
        else            ws_decay[r - 3 * ID] = 1.f / (1.f + expf(-acc));
    }
}

// Kernel 2: 256 blocks (h = b&15, s = b>>4) x 1024 threads.
//  - Preload Wout slice (2 v4f/thread) + state slice (1 float/thread); asm
//    keepalive pins the loads before the z-matvec / rendezvous.
//  - waves 0..7: one W_z row each (rows 128h+8s+wv) -> silu -> atomicExch zsig.
//  - state update for d in [8s,8s+8): sn = sv*decay + k*v; write new_state;
//    ypart[h][e] += q_d*sn via LDS partial + agent atomicAdd.
//  - 16-way per-head rendezvous (blocks of head h all live on XCD h%8).
//  - RMSNorm + gate from ypart+zsig; Wout partial rows [64s,64s+64) from regs;
//    atomicAdd into out.
__global__ __launch_bounds__(1024) void state_z_gate_out(
    const float* __restrict__ x,
    const float* __restrict__ state_in,
    const float* __restrict__ Wz,
    const float* __restrict__ normw,
    const float* __restrict__ Wout,
    float* __restrict__ state_out,
    float* __restrict__ out,
    float* __restrict__ ws)
{
    int*   cnt      = (int*)ws;
    float* ypart    = ws + 64;
    float* ws_zsig  = ws + 2112;
    float* ws_qkv   = ws + 4160;
    float* ws_decay = ws + 10304;

    const int b  = blockIdx.x;
    const int h  = b & 15;
    const int s  = b >> 4;
    const int t  = threadIdx.x;
    const int wv = t >> 6;
    const int lane = t & 63;

    __shared__ float lds_part[8][HD];
    __shared__ float lds_g[HD];
    __shared__ float red2[2];

    // ---- independent streams issued up front ----
    const int rl = t >> 4, j = t & 15;
    const int orow = s * 64 + rl;
    const v4f* wrow = (const v4f*)(Wout + (size_t)orow * ID + h * HD);
    v4f w0 = wrow[2 * j];
    v4f w1 = wrow[2 * j + 1];

    const int sd = t >> 7, se = t & 127;
    const int d  = s * 8 + sd;
    const size_t sidx = (size_t)h * HD * HD + (size_t)d * HD + se;
    float sv = state_in[sidx];
    asm volatile("" : "+v"(w0), "+v"(w1), "+v"(sv));

    // ---- z matvec: waves 0..7, one row each ----
    if (wv < 8) {
        const int zr = h * HD + s * 8 + wv;   // 0..2047
        const float4* row4 = (const float4*)(Wz + (size_t)zr * H);
        const float4* x4   = (const float4*)x;
        float acc = 0.f;
#pragma unroll
        for (int i = 0; i < 4; ++i) {
            float4 w  = row4[lane + 64 * i];
            float4 xv = x4[lane + 64 * i];
            acc += w.x * xv.x + w.y * xv.y + w.z * xv.z + w.w * xv.w;
        }
        acc = waveReduceSum(acc);
        if (lane == 0) AXCH(&ws_zsig[zr], acc / (1.f + expf(-acc)));
    }

    // ---- state update + ypart partial ----
    {
        const float decay = ws_decay[h];
        const float qd = ws_qkv[h * HD + d];
        const float kd = ws_qkv[ID + h * HD + d];
        const float ve = ws_qkv[2 * ID + h * HD + se];
        const float sn = sv * decay + kd * ve;
        state_out[sidx] = sn;
        lds_part[sd][se] = qd * sn;
    }
    __syncthreads();
    if (t < HD) {
        float y8 = 0.f;
#pragma unroll
        for (int d2 = 0; d2 < 8; ++d2) y8 += lds_part[d2][t];
        atomicAdd(&ypart[h * HD + t], y8);
    }
    __syncthreads();   // all z-exch + ypart-adds performed before release

    // ---- per-head 16-way rendezvous ----
    if (t == 0) {
        AADD_REL(&cnt[h], 1);
        while (ALOAD_ACQ(&cnt[h]) < 16) __builtin_amdgcn_s_sleep(1);
    }
    __syncthreads();

    // ---- RMSNorm + silu(z) gate ----
    float yv = 0.f;
    if (t < HD) {
        yv = ALOAD(&ypart[h * HD + t]);
        float s2 = yv * yv;
#pragma unroll
        for (int off = 1; off < 64; off <<= 1) s2 += __shfl_xor(s2, off, 64);
        if (lane == 0) red2[t >> 6] = s2;
    }
    __syncthreads();
    if (t < HD) {
        const float scale = rsqrtf((red2[0] + red2[1]) * (1.f / HD) + EPS);
        const float zs = ALOAD(&ws_zsig[h * HD + t]);
        lds_g[t] = yv * scale * normw[t] * zs;
    }
    __syncthreads();

    // ---- Wout partial from registers ----
    {
        const v4f* g4 = (const v4f*)lds_g;
        const v4f g0 = g4[2 * j], g1 = g4[2 * j + 1];
        float a = w0.x * g0.x + w0.y * g0.y + w0.z * g0.z + w0.w * g0.w
                + w1.x * g1.x + w1.y * g1.y + w1.z * g1.z + w1.w * g1.w;
        a += __shfl_xor(a, 1, 64);
        a += __shfl_xor(a, 2, 64);
        a += __shfl_xor(a, 4, 64);
        a += __shfl_xor(a, 8, 64);
        if (j == 0) atomicAdd(&out[orow], a);
    }
}

extern "C" void kernel_launch(void* const* d_in, const int* in_sizes, int n_in,
                              void* d_out, int out_size, void* d_ws, size_t ws_size,
                              hipStream_t stream) {
    const float* x     = (const float*)d_in[0];
    const float* state = (const float*)d_in[1];
    const float* conv  = (const float*)d_in[2];
    const float* Wqkv  = (const float*)d_in[3];
    const float* Wz    = (const float*)d_in[4];
    const float* Wa    = (const float*)d_in[5];
    const float* normw = (const float*)d_in[6];
    const float* Wout  = (const float*)d_in[7];

    float* out       = (float*)d_out;                    // [1024]
    float* new_state = out + H;                          // [16*128*128]
    float* conv_out  = new_state + (size_t)NH * HD * HD; // [18432]
    float* ws        = (float*)d_ws;

    matvec_qkva<<<K1_MATVEC_BLOCKS + CONV_BLOCKS, 256, 0, stream>>>(
        x, Wqkv, Wa, conv, conv_out, out, ws);
    state_z_gate_out<<<256, 1024, 0, stream>>>(
        x, state, Wz, normw, Wout, new_state, out, ws);
}

// Round 11
// 18.197 us; speedup vs baseline: 2.4659x; 1.4457x over previous
//
#include <hip/hip_runtime.h>
#include <math.h>

#define H    1024
#define NH   16
#define HD   128
#define ID   2048                 // NH*HD
#define NROWS_A (3*ID + ID + NH)  // 6144 qkv + 2048 z + 16 a = 8208
#define NWAVES2 (NROWS_A / 2)     // 4104 waves, 2 rows each
#define MATVEC_BLOCKS (NWAVES2 / 4)   // 1026 blocks of 4 waves
#define CONV_FLOATS (3 * ID * 3)      // 18432 floats = 4608 float4
#define CONV_BLOCKS (CONV_FLOATS / 4 / 256)  // 18
#define EPS 1e-6f

__device__ __forceinline__ float waveReduceSumAll(float v) {
#pragma unroll
    for (int off = 1; off < 64; off <<= 1) v += __shfl_xor(v, off, 64);
    return v;
}

// Kernel 1: fused matvec, 2 rows per wave (8 independent float4 loads/lane in
// flight = 2x the MLP of 1-row/wave) while keeping 1044 blocks (~4/CU tail).
// Waves 0..3071 -> qkv rows, 3072..4095 -> z rows, 4096..4103 -> a rows.
// Trailing blocks: conv passthrough + out[] zeroing.
__global__ __launch_bounds__(256) void matvec_qkvza(
    const float* __restrict__ x,
    const float* __restrict__ Wqkv,
    const float* __restrict__ Wz,
    const float* __restrict__ Wa,
    const float* __restrict__ conv,
    float* __restrict__ conv_out,
    float* __restrict__ out,       // zeroed here (K2 atomicAdds into it)
    float* __restrict__ ws_qkv,    // [6144] q|k|v
    float* __restrict__ ws_zsig,   // [2048] z*sigmoid(z)
    float* __restrict__ ws_decay)  // [16] sigmoid(a)
{
    if (blockIdx.x >= MATVEC_BLOCKS) {
        const int cb = blockIdx.x - MATVEC_BLOCKS;
        const int i = cb * 256 + threadIdx.x;
        ((float4*)conv_out)[i] = ((const float4*)conv)[i];
        if (cb == 0) {   // zero out[1024] = 256 float4
            float4 z4 = {0.f, 0.f, 0.f, 0.f};
            ((float4*)out)[threadIdx.x] = z4;
        }
        return;
    }

    const int wave = threadIdx.x >> 6;
    const int lane = threadIdx.x & 63;
    const int r0 = (blockIdx.x * 4 + wave) * 2;   // first of 2 consecutive rows

    const float* base;
    int kind;                               // 0=qkv, 1=z, 2=a (wave-uniform)
    if (r0 < 3 * ID)      { base = Wqkv + (size_t)r0 * H;            kind = 0; }
    else if (r0 < 4 * ID) { base = Wz + (size_t)(r0 - 3 * ID) * H;   kind = 1; }
    else                  { base = Wa + (size_t)(r0 - 4 * ID) * H;   kind = 2; }

    const float4* b4 = (const float4*)base;   // row stride = 256 float4
    const float4* x4 = (const float4*)x;

    float4 xv[4];
#pragma unroll
    for (int i = 0; i < 4; ++i) xv[i] = x4[lane + 64 * i];

    // 8 independent row loads issued before any use
    float4 wa[4], wb[4];
#pragma unroll
    for (int i = 0; i < 4; ++i) { wa[i] = b4[lane + 64 * i]; wb[i] = b4[256 + lane + 64 * i]; }

    float a0 = 0.f, a1 = 0.f;
#pragma unroll
    for (int i = 0; i < 4; ++i) {
        a0 += wa[i].x * xv[i].x + wa[i].y * xv[i].y + wa[i].z * xv[i].z + wa[i].w * xv[i].w;
        a1 += wb[i].x * xv[i].x + wb[i].y * xv[i].y + wb[i].z * xv[i].z + wb[i].w * xv[i].w;
    }
    // two parallel butterflies pipeline through the crossbar
#pragma unroll
    for (int off = 1; off < 64; off <<= 1) {
        a0 += __shfl_xor(a0, off, 64);
        a1 += __shfl_xor(a1, off, 64);
    }

    if (lane == 0) {
        if (kind == 0) {
            float2 o = {a0, a1};
            *(float2*)(ws_qkv + r0) = o;
        } else if (kind == 1) {
            float2 o;
            o.x = a0 / (1.f + expf(-a0));
            o.y = a1 / (1.f + expf(-a1));
            *(float2*)(ws_zsig + (r0 - 3 * ID)) = o;
        } else {
            float2 o;
            o.x = 1.f / (1.f + expf(-a0));
            o.y = 1.f / (1.f + expf(-a1));
            *(float2*)(ws_decay + (r0 - 4 * ID)) = o;
        }
    }
}

// Kernel 2 (identical to round-7 champion): 256 blocks = (slice s = b>>4,
// head h = b&15) x 1024 threads. b = s*16 + h so all 16 slice-blocks of head
// h share b%8 -> same XCD L2. Each block: preload its Wout slice into regs,
// read the FULL 128x128 state of head h, sn = s*decay + k (outer) v; wave s
// writes its 8 d-rows; reduce y[e] in-block; RMSNorm + silu-gate; Wout
// partial rows [64s,64s+64) x cols of head h; atomicAdd into out.
__global__ __launch_bounds__(1024) void state_gate_out(
    const float* __restrict__ state_in,
    const float* __restrict__ ws_qkv,
    const float* __restrict__ ws_decay,
    const float* __restrict__ ws_zsig,
    const float* __restrict__ normw,
    const float* __restrict__ Wout,
    float* __restrict__ state_out,
    float* __restrict__ out)
{
    const int s  = blockIdx.x >> 4;
    const int h  = blockIdx.x & 15;
    const int t  = threadIdx.x;
    const int c  = t & 31;     // float4 column (e = 4c..4c+3)
    const int dg = t >> 5;     // 0..31, covers d = 4dg..4dg+3
    const int wv = t >> 6;     // wave, covers d in [8wv, 8wv+8)
    const int lane = t & 63;

    __shared__ float4 part4[16][32];   // 8 KB per-wave y partials
    __shared__ float gated[HD];
    __shared__ float red2[2];

    // ---- Wout register preload (no dependency; overlaps the state chain) ----
    const int rl = t >> 4;            // 0..63
    const int j  = t & 15;
    const int r  = s * 64 + rl;
    const float4* wrow = (const float4*)(Wout + (size_t)r * ID + h * HD);
    const float4 w0 = wrow[j * 2];
    const float4 w1 = wrow[j * 2 + 1];

    const float decay = ws_decay[h];
    const float4 vv = ((const float4*)(ws_qkv + 2 * ID + h * HD))[c];
    const float4 q4 = ((const float4*)(ws_qkv + h * HD))[dg];
    const float4 k4 = ((const float4*)(ws_qkv + ID + h * HD))[dg];

    const float4* sin4 = (const float4*)(state_in  + (size_t)h * HD * HD);
    float4*       sout = (float4*)(state_out + (size_t)h * HD * HD);

    const bool do_write = (wv == s);   // wave-uniform

    float4 acc = {0.f, 0.f, 0.f, 0.f};
    const float qs[4] = {q4.x, q4.y, q4.z, q4.w};
    const float ks[4] = {k4.x, k4.y, k4.z, k4.w};
#pragma unroll
    for (int i = 0; i < 4; ++i) {
        const int d = dg * 4 + i;
        const float4 sv = sin4[d * 32 + c];
        float4 sn;
        sn.x = sv.x * decay + ks[i] * vv.x;
        sn.y = sv.y * decay + ks[i] * vv.y;
        sn.z = sv.z * decay + ks[i] * vv.z;
        sn.w = sv.w * decay + ks[i] * vv.w;
        if (do_write) sout[d * 32 + c] = sn;
        acc.x += qs[i] * sn.x;
        acc.y += qs[i] * sn.y;
        acc.z += qs[i] * sn.z;
        acc.w += qs[i] * sn.w;
    }
    acc.x += __shfl_xor(acc.x, 32, 64);
    acc.y += __shfl_xor(acc.y, 32, 64);
    acc.z += __shfl_xor(acc.z, 32, 64);
    acc.w += __shfl_xor(acc.w, 32, 64);
    if (lane < 32) part4[wv][c] = acc;
    __syncthreads();

    const float* partF = (const float*)part4;
    float y = 0.f;
    if (t < HD) {
#pragma unroll
        for (int w2 = 0; w2 < 16; ++w2) y += partF[w2 * HD + t];
        const float s2 = waveReduceSumAll(y * y);
        if (lane == 0) red2[t >> 6] = s2;
    }
    __syncthreads();
    if (t < HD) {
        const float scale = rsqrtf((red2[0] + red2[1]) * (1.f / HD) + EPS);
        gated[t] = y * scale * normw[t] * ws_zsig[h * HD + t];
    }
    __syncthreads();

    {
        const float4* g4 = (const float4*)gated;
        const float4 g0 = g4[j * 2], g1 = g4[j * 2 + 1];
        float a = w0.x * g0.x + w0.y * g0.y + w0.z * g0.z + w0.w * g0.w
                + w1.x * g1.x + w1.y * g1.y + w1.z * g1.z + w1.w * g1.w;
        a += __shfl_xor(a, 1, 64);
        a += __shfl_xor(a, 2, 64);
        a += __shfl_xor(a, 4, 64);
        a += __shfl_xor(a, 8, 64);
        if (j == 0) atomicAdd(&out[r], a);
    }
}

extern "C" void kernel_launch(void* const* d_in, const int* in_sizes, int n_in,
                              void* d_out, int out_size, void* d_ws, size_t ws_size,
                              hipStream_t stream) {
    const float* x     = (const float*)d_in[0];
    const float* state = (const float*)d_in[1];
    const float* conv  = (const float*)d_in[2];
    const float* Wqkv  = (const float*)d_in[3];
    const float* Wz    = (const float*)d_in[4];
    const float* Wa    = (const float*)d_in[5];
    const float* normw = (const float*)d_in[6];
    const float* Wout  = (const float*)d_in[7];

    float* out       = (float*)d_out;                    // [1024]
    float* new_state = out + H;                          // [16*128*128]
    float* conv_out  = new_state + (size_t)NH * HD * HD; // [18432]

    float* ws       = (float*)d_ws;
    float* ws_qkv   = ws;               // 6144
    float* ws_zsig  = ws + 6144;        // 2048
    float* ws_decay = ws + 8192;        // 16

    matvec_qkvza<<<MATVEC_BLOCKS + CONV_BLOCKS, 256, 0, stream>>>(
        x, Wqkv, Wz, Wa, conv, conv_out, out, ws_qkv, ws_zsig, ws_decay);
    state_gate_out<<<NH * 16, 1024, 0, stream>>>(
        state, ws_qkv, ws_decay, ws_zsig, normw, Wout, new_state, out);
}

// Round 12
// 16.416 us; speedup vs baseline: 2.7336x; 1.1085x over previous
//
#include <hip/hip_runtime.h>
#include <math.h>

#define H    1024
#define NH   16
#define HD   128
#define ID   2048                 // NH*HD
#define NROWS_A (3*ID + ID + NH)  // 6144 qkv + 2048 z + 16 a = 8208
#define MATVEC_BLOCKS (NROWS_A / 4)   // 2052, one row per wave
#define CONV_FLOATS (3 * ID * 3)      // 18432 floats = 4608 float4
#define CONV_BLOCKS (CONV_FLOATS / 4 / 256)  // 18
#define EPS 1e-6f

typedef float v4f __attribute__((ext_vector_type(4)));

__device__ __forceinline__ float waveReduceSum(float v) {
#pragma unroll
    for (int off = 32; off > 0; off >>= 1) v += __shfl_down(v, off, 64);
    return v;
}
__device__ __forceinline__ float waveReduceSumAll(float v) {
#pragma unroll
    for (int off = 1; off < 64; off <<= 1) v += __shfl_xor(v, off, 64);
    return v;
}

// Kernel 1 (R7 structure): fused matvec of x against W_qkv/W_z/W_a, one row
// per wave. Single-use weight rows use NONTEMPORAL loads (nt flag) to skip
// cache allocation; x stays cached (reused by every wave).
__global__ __launch_bounds__(256) void matvec_qkvza(
    const float* __restrict__ x,
    const float* __restrict__ Wqkv,
    const float* __restrict__ Wz,
    const float* __restrict__ Wa,
    const float* __restrict__ conv,
    float* __restrict__ conv_out,
    float* __restrict__ out,       // zeroed here (K2 atomicAdds into it)
    float* __restrict__ ws_qkv,    // [6144] q|k|v
    float* __restrict__ ws_zsig,   // [2048] z*sigmoid(z)
    float* __restrict__ ws_decay)  // [16] sigmoid(a)
{
    if (blockIdx.x >= MATVEC_BLOCKS) {
        const int cb = blockIdx.x - MATVEC_BLOCKS;
        const int i = cb * 256 + threadIdx.x;
        ((float4*)conv_out)[i] = ((const float4*)conv)[i];
        if (cb == 0) {   // zero out[1024] = 256 float4
            float4 z4 = {0.f, 0.f, 0.f, 0.f};
            ((float4*)out)[threadIdx.x] = z4;
        }
        return;
    }

    const int wave = threadIdx.x >> 6;
    const int lane = threadIdx.x & 63;
    const int r = blockIdx.x * 4 + wave;

    const float* row;
    if (r < 3 * ID)           row = Wqkv + (size_t)r * H;
    else if (r < 3 * ID + ID) row = Wz   + (size_t)(r - 3 * ID) * H;
    else                      row = Wa   + (size_t)(r - 3 * ID - ID) * H;

    const v4f* row4 = (const v4f*)row;
    const v4f* x4   = (const v4f*)x;

    float acc = 0.f;
#pragma unroll
    for (int t = 0; t < 4; ++t) {
        const v4f w  = __builtin_nontemporal_load(&row4[lane + 64 * t]);
        const v4f xv = x4[lane + 64 * t];
        acc += w.x * xv.x + w.y * xv.y + w.z * xv.z + w.w * xv.w;
    }
    acc = waveReduceSum(acc);
    if (lane == 0) {
        if (r < 3 * ID) {
            ws_qkv[r] = acc;
        } else if (r < 3 * ID + ID) {
            const float sig = 1.f / (1.f + expf(-acc));
            ws_zsig[r - 3 * ID] = acc * sig;
        } else {
            ws_decay[r - 3 * ID - ID] = 1.f / (1.f + expf(-acc));
        }
    }
}

// Kernel 2 (R7 champion structure): 256 blocks = (slice s = b>>4, head h =
// b&15) x 1024 threads; same-h blocks share XCD h%8 L2 so the full-head state
// read is fetched from HBM ~once per head. Wout rows (single-use) loaded
// nontemporally into registers up front; state stays cached (16x reuse).
__global__ __launch_bounds__(1024) void state_gate_out(
    const float* __restrict__ state_in,
    const float* __restrict__ ws_qkv,
    const float* __restrict__ ws_decay,
    const float* __restrict__ ws_zsig,
    const float* __restrict__ normw,
    const float* __restrict__ Wout,
    float* __restrict__ state_out,
    float* __restrict__ out)
{
    const int s  = blockIdx.x >> 4;
    const int h  = blockIdx.x & 15;
    const int t  = threadIdx.x;
    const int c  = t & 31;     // float4 column (e = 4c..4c+3)
    const int dg = t >> 5;     // 0..31, covers d = 4dg..4dg+3
    const int wv = t >> 6;     // wave, covers d in [8wv, 8wv+8)
    const int lane = t & 63;

    __shared__ float4 part4[16][32];   // 8 KB per-wave y partials
    __shared__ float gated[HD];
    __shared__ float red2[2];

    // ---- Wout register preload, nontemporal (single-use stream) ----
    const int rl = t >> 4;            // 0..63
    const int j  = t & 15;
    const int r  = s * 64 + rl;
    const v4f* wrow = (const v4f*)(Wout + (size_t)r * ID + h * HD);
    const v4f w0 = __builtin_nontemporal_load(&wrow[j * 2]);
    const v4f w1 = __builtin_nontemporal_load(&wrow[j * 2 + 1]);

    const float decay = ws_decay[h];
    const float4 vv = ((const float4*)(ws_qkv + 2 * ID + h * HD))[c];
    const float4 q4 = ((const float4*)(ws_qkv + h * HD))[dg];
    const float4 k4 = ((const float4*)(ws_qkv + ID + h * HD))[dg];

    const float4* sin4 = (const float4*)(state_in  + (size_t)h * HD * HD);
    float4*       sout = (float4*)(state_out + (size_t)h * HD * HD);

    const bool do_write = (wv == s);   // wave-uniform

    float4 acc = {0.f, 0.f, 0.f, 0.f};
    const float qs[4] = {q4.x, q4.y, q4.z, q4.w};
    const float ks[4] = {k4.x, k4.y, k4.z, k4.w};
#pragma unroll
    for (int i = 0; i < 4; ++i) {
        const int d = dg * 4 + i;
        const float4 sv = sin4[d * 32 + c];
        float4 sn;
        sn.x = sv.x * decay + ks[i] * vv.x;
        sn.y = sv.y * decay + ks[i] * vv.y;
        sn.z = sv.z * decay + ks[i] * vv.z;
        sn.w = sv.w * decay + ks[i] * vv.w;
        if (do_write) sout[d * 32 + c] = sn;
        acc.x += qs[i] * sn.x;
        acc.y += qs[i] * sn.y;
        acc.z += qs[i] * sn.z;
        acc.w += qs[i] * sn.w;
    }
    acc.x += __shfl_xor(acc.x, 32, 64);
    acc.y += __shfl_xor(acc.y, 32, 64);
    acc.z += __shfl_xor(acc.z, 32, 64);
    acc.w += __shfl_xor(acc.w, 32, 64);
    if (lane < 32) part4[wv][c] = acc;
    __syncthreads();

    const float* partF = (const float*)part4;
    float y = 0.f;
    if (t < HD) {
#pragma unroll
        for (int w2 = 0; w2 < 16; ++w2) y += partF[w2 * HD + t];
        const float s2 = waveReduceSumAll(y * y);
        if (lane == 0) red2[t >> 6] = s2;
    }
    __syncthreads();
    if (t < HD) {
        const float scale = rsqrtf((red2[0] + red2[1]) * (1.f / HD) + EPS);
        gated[t] = y * scale * normw[t] * ws_zsig[h * HD + t];
    }
    __syncthreads();

    {
        const v4f* g4 = (const v4f*)gated;
        const v4f g0 = g4[j * 2], g1 = g4[j * 2 + 1];
        float a = w0.x * g0.x + w0.y * g0.y + w0.z * g0.z + w0.w * g0.w
                + w1.x * g1.x + w1.y * g1.y + w1.z * g1.z + w1.w * g1.w;
        a += __shfl_xor(a, 1, 64);
        a += __shfl_xor(a, 2, 64);
        a += __shfl_xor(a, 4, 64);
        a += __shfl_xor(a, 8, 64);
        if (j == 0) atomicAdd(&out[r], a);
    }
}

extern "C" void kernel_launch(void* const* d_in, const int* in_sizes, int n_in,
                              void* d_out, int out_size, void* d_ws, size_t ws_size,
                              hipStream_t stream) {
    const float* x     = (const float*)d_in[0];
    const float* state = (const float*)d_in[1];
    const float* conv  = (const float*)d_in[2];
    const float* Wqkv  = (const float*)d_in[3];
    const float* Wz    = (const float*)d_in[4];
    const float* Wa    = (const float*)d_in[5];
    const float* normw = (const float*)d_in[6];
    const float* Wout  = (const float*)d_in[7];

    float* out       = (float*)d_out;                    // [1024]
    float* new_state = out + H;                          // [16*128*128]
    float* conv_out  = new_state + (size_t)NH * HD * HD; // [18432]

    float* ws       = (float*)d_ws;
    float* ws_qkv   = ws;               // 6144
    float* ws_zsig  = ws + 6144;        // 2048
    float* ws_decay = ws + 8192;        // 16

    matvec_qkvza<<<MATVEC_BLOCKS + CONV_BLOCKS, 256, 0, stream>>>(
        x, Wqkv, Wz, Wa, conv, conv_out, out, ws_qkv, ws_zsig, ws_decay);
    state_gate_out<<<NH * 16, 1024, 0, stream>>>(
        state, ws_qkv, ws_decay, ws_zsig, normw, Wout, new_state, out);
}